// Round 6
// baseline (430.282 us; speedup 1.0000x reference)
//
#include <hip/hip_runtime.h>

#define S    4
#define BB   8
#define CC   64
#define HH   128
#define WW   256
#define KC   8            // channels per LDS chunk
#define TH   8            // rows per block tile
#define TW   64           // cols per block tile
#define PX   8            // pixels per thread
#define NTX  8            // TW / PX
#define NG   9            // one wave per di
#define NT   576          // 9 waves
#define TROWS 16          // TH + 2S
#define PITCH 76          // 19 quads exactly -> staged chunk is LINEAR in lane order
#define NQ   19
#define CHUNKF (KC * TROWS * PITCH)   // 9728 floats per buffer
#define F4C  (KC * TROWS * NQ)        // 2432 float4 per chunk
#define NCH  (CC / KC)                // 8 chunks

// Map displacement (di,dj) -> output index in the reference's enumeration order.
__device__ __host__ constexpr int ord_idx(int di, int dj) {
  int i = di < 0 ? -di : di;
  int j = dj < 0 ? -dj : dj;
  if (i == 0 && j == 0) return 0;
  if (j == 0) return 1 + (i - 1) * 20 + (di > 0 ? 0 : 1);
  if (i == 0) return 1 + (j - 1) * 20 + (dj > 0 ? 2 : 3);
  return 1 + (i - 1) * 20 + 4 + (j - 1) * 4 +
         (di > 0 ? (dj > 0 ? 0 : 2) : (dj > 0 ? 1 : 3));
}

#define GLD_LDS(G, L)                                                       \
  __builtin_amdgcn_global_load_lds(                                         \
      (const __attribute__((address_space(1))) void*)(G),                   \
      (__attribute__((address_space(3))) void*)(L), 16, 0, 0)

__global__ __launch_bounds__(NT, 2)   // 256-VGPR budget: do NOT spill
void costvol_kernel(const float* __restrict__ src,
                    const float* __restrict__ tgt,
                    const float* __restrict__ zws,   // >=1KB of zeros (d_ws)
                    float* __restrict__ out) {
  __shared__ __align__(16) float lds[2][CHUNKF];     // 77,824 B

  const int tx  = threadIdx.x;           // 0..7
  const int ty  = threadIdx.y;           // 0..7
  const int tz  = threadIdx.z;           // 0..8 ; wave index; di = tz - 4
  const int tid = (tz * TH + ty) * NTX + tx;

  // XCD-aware bijective swizzle: each XCD owns one batch image (64 tiles).
  const int lin  = blockIdx.x;
  const int lin2 = (lin & 7) * 64 + (lin >> 3);
  const int bx = lin2 & 3;
  const int by = (lin2 >> 2) & 15;
  const int b  = lin2 >> 6;

  const int w0b = bx * TW;
  const int h0  = by * TH;
  const int h   = h0 + ty;
  const int w0  = w0b + tx * PX;
  const int di  = tz - S;                // wave-uniform
  const int row = ty + 2 * S - tz;       // staged row this thread reads (0..15)

  // ---- staging descriptors (chunk-0 global base per k; LDS offset = f*16B) ----
  const float* gp[5];
  int lofs[5];
  int gok[5];
#pragma unroll
  for (int k = 0; k < 5; ++k) {
    const int f = tid + k * NT;
    lofs[k] = f * 4;                     // float offset (linear: PITCH==NQ*4)
    gok[k]  = 0;
    gp[k]   = zws;
    if (f < F4C) {
      const int c   = f / (TROWS * NQ);        // /304
      const int rem = f - c * (TROWS * NQ);
      const int r   = rem / NQ;
      const int q   = rem - r * NQ;
      const int gh  = h0 - S + r;
      const int gw  = w0b - S + 4 * q;         // 16B aligned
      if ((unsigned)gh < (unsigned)HH && gw >= 0 && gw + 3 < WW) {
        gok[k] = 1;
        gp[k]  = tgt + ((size_t)(b * CC + c) * HH + gh) * WW + gw;
      }
    }
  }

  // Issue one chunk's async global->LDS loads. k=4 covers f=2304..2431 -> tz<2 only
  // (wave-uniform branch). OOB lanes pull 16B of zeros from zws (no masking).
#define ISSUE(CH, SEL) do {                                                 \
    float* lb = &lds[SEL][0];                                               \
    const size_t coff = (size_t)(CH) * (KC * HH * WW);                      \
    _Pragma("unroll")                                                       \
    for (int k = 0; k < 4; ++k) {                                           \
      const float* g = gok[k] ? gp[k] + coff : zws;                         \
      GLD_LDS(g, lb + lofs[k]);                                             \
    }                                                                       \
    if (tz < 2) {                                                           \
      const float* g = gok[4] ? gp[4] + coff : zws;                         \
      GLD_LDS(g, lb + lofs[4]);                                             \
    }                                                                       \
  } while (0)

  float acc[9][PX];
#pragma unroll
  for (int o = 0; o < 9; ++o)
#pragma unroll
    for (int k = 0; k < PX; ++k) acc[o][k] = 0.f;

  const float* srcbase = src + ((size_t)b * CC * HH + h) * WW + w0;

  int sel = 0;
  ISSUE(0, 0);
  __syncthreads();                       // drains vmcnt -> buf0 staged

  for (int ch = 0; ch < NCH; ++ch) {
    if (ch + 1 < NCH) ISSUE(ch + 1, sel ^ 1);   // prefetch under compute

    const float* lb = &lds[sel][0];
    const float* sch = srcbase + (size_t)ch * (KC * HH * WW);
#pragma unroll
    for (int c = 0; c < KC; ++c) {
      const float* sp = sch + (size_t)c * (HH * WW);
      const float4 s0 = *reinterpret_cast<const float4*>(sp);
      const float4 s1 = *reinterpret_cast<const float4*>(sp + 4);
      const float sv[PX] = {s0.x, s0.y, s0.z, s0.w, s1.x, s1.y, s1.z, s1.w};

      // 16-float window: 4 aligned ds_read_b128 from this thread's own row
      const float4* rp = reinterpret_cast<const float4*>(
          lb + c * (TROWS * PITCH) + row * PITCH + tx * PX);
      float win[16];
#pragma unroll
      for (int q = 0; q < 4; ++q) {
        const float4 t = rp[q];
        win[4 * q]     = t.x;
        win[4 * q + 1] = t.y;
        win[4 * q + 2] = t.z;
        win[4 * q + 3] = t.w;
      }

#pragma unroll
      for (int dj = -S; dj <= S; ++dj) {
#pragma unroll
        for (int k = 0; k < PX; ++k)
          acc[dj + S][k] += sv[k] * win[k + S - dj];
      }
    }

    __syncthreads();                     // drain prefetch + release buf[sel]
    sel ^= 1;
  }

  // ---- store: 9 dj x 2 coalesced float4 stores ----
  const size_t HW = (size_t)HH * WW;
  float* op = out + (size_t)b * 81 * HW + (size_t)h * WW + w0;
#pragma unroll
  for (int dj = -S; dj <= S; ++dj) {
    const int o    = ord_idx(di, dj);    // wave-uniform scalar epilogue
    const int slot = dj + S;
    *reinterpret_cast<float4*>(op + (size_t)o * HW) =
        make_float4(acc[slot][0], acc[slot][1], acc[slot][2], acc[slot][3]);
    *reinterpret_cast<float4*>(op + (size_t)o * HW + 4) =
        make_float4(acc[slot][4], acc[slot][5], acc[slot][6], acc[slot][7]);
  }
}

extern "C" void kernel_launch(void* const* d_in, const int* in_sizes, int n_in,
                              void* d_out, int out_size, void* d_ws, size_t ws_size,
                              hipStream_t stream) {
  const float* src = (const float*)d_in[0];
  const float* tgt = (const float*)d_in[1];
  float* out = (float*)d_out;
  // Zero region for OOB halo lanes (d_ws is NOT re-poisoned between replays,
  // but we re-zero every call -> deterministic).
  hipMemsetAsync(d_ws, 0, 1024, stream);
  // search_range (d_in[2]) is fixed at 4 per setup_inputs; geometry hardcoded.
  dim3 grid(512, 1, 1);                // 4 bx * 16 by * 8 b, swizzled in-kernel
  dim3 block(NTX, TH, NG);             // 576 threads = 9 waves
  costvol_kernel<<<grid, block, 0, stream>>>(src, tgt, (const float*)d_ws, out);
}

// Round 7
// 105.377 us; speedup vs baseline: 4.0833x; 4.0833x over previous
//
#include <hip/hip_runtime.h>

#define S    4
#define BB   8
#define CC   64
#define HH   128
#define WW   256
#define KC   4            // channels per LDS chunk (single buffer)
#define TH   4            // tile rows
#define TW   128          // tile cols
#define PX   8            // pixels per thread
#define NTX  16           // TW / PX ; 16 lanes per row -> R4's 0-conflict pattern
#define NTY  4
#define NG   9            // one wave per di
#define NT   576          // 9 waves
#define TROWS 12          // TH + 2S
#define PITCH 140         // 35 quads; 140%32=12 -> proven conflict-free (R4)
#define NQ   35
#define F4C  (KC * TROWS * NQ)   // 1680 float4 per chunk
#define NCH  (CC / KC)           // 16 chunks

// Map displacement (di,dj) -> output index in the reference's enumeration order.
__device__ __host__ constexpr int ord_idx(int di, int dj) {
  int i = di < 0 ? -di : di;
  int j = dj < 0 ? -dj : dj;
  if (i == 0 && j == 0) return 0;
  if (j == 0) return 1 + (i - 1) * 20 + (di > 0 ? 0 : 1);
  if (i == 0) return 1 + (j - 1) * 20 + (dj > 0 ? 2 : 3);
  return 1 + (i - 1) * 20 + 4 + (j - 1) * 4 +
         (di > 0 ? (dj > 0 ? 0 : 2) : (dj > 0 ? 1 : 3));
}

__global__ __launch_bounds__(NT, 2)
void costvol_kernel(const float* __restrict__ src,
                    const float* __restrict__ tgt,
                    float* __restrict__ out) {
  __shared__ __align__(16) float lds[KC][TROWS][PITCH];   // 26,880 B

  const int tx  = threadIdx.x;           // 0..15
  const int ty  = threadIdx.y;           // 0..3
  const int tz  = threadIdx.z;           // 0..8 ; wave index; di = tz - 4
  const int tid = (tz * NTY + ty) * NTX + tx;

  // XCD-aware bijective swizzle: each XCD owns one batch image (64 tiles)
  // -> vertical-halo rows shared between by+-1 tiles hit the same L2.
  const int lin  = blockIdx.x;
  const int lin2 = (lin & 7) * 64 + (lin >> 3);
  const int bx = lin2 & 1;               // 0..1
  const int by = (lin2 >> 1) & 31;       // 0..31
  const int b  = lin2 >> 6;              // 0..7

  const int w0b = bx * TW;
  const int h0  = by * TH;
  const int h   = h0 + ty;
  const int w0  = w0b + tx * PX;
  const int di  = tz - S;                // wave-uniform
  const int row = ty + S - di;           // staged row this thread reads (0..11)

  // ---- staging descriptors: 3x (lds float-offset, global elem-offset) ----
  int lofs[3], goff[3];
#pragma unroll
  for (int k = 0; k < 3; ++k) {
    const int f = tid + k * NT;
    lofs[k] = -1; goff[k] = -1;
    if (f < F4C) {
      const int c   = f / (TROWS * NQ);        // /420
      const int rem = f - c * (TROWS * NQ);
      const int r   = rem / NQ;                // /35
      const int q   = rem - r * NQ;
      const int gh  = h0 - S + r;
      const int gw  = w0b - S + 4 * q;         // 16B aligned
      lofs[k] = (c * TROWS + r) * PITCH + 4 * q;
      if ((unsigned)gh < (unsigned)HH && gw >= 0 && gw + 3 < WW)
        goff[k] = ((b * CC + c) * HH + gh) * WW + gw;   // fits int32
    }
  }

  float acc[9][PX];
#pragma unroll
  for (int o = 0; o < 9; ++o)
#pragma unroll
    for (int k = 0; k < PX; ++k) acc[o][k] = 0.f;

  const float* srcrow = src + ((size_t)b * CC * HH + h) * WW + w0;
  float* lbase = &lds[0][0][0];

  for (int ch = 0; ch < NCH; ++ch) {
    __syncthreads();                     // previous chunk's readers done

    // ---- stage: plain reg-path, barrier-separated (R4-proven clean) ----
    const int choff = ch * (KC * HH * WW);
#pragma unroll
    for (int k = 0; k < 3; ++k) {
      if (lofs[k] >= 0) {
        float4 v = make_float4(0.f, 0.f, 0.f, 0.f);
        if (goff[k] >= 0)
          v = *reinterpret_cast<const float4*>(tgt + goff[k] + choff);
        *reinterpret_cast<float4*>(lbase + lofs[k]) = v;
      }
    }

    __syncthreads();                     // chunk staged

    // ---- compute: unroll 2 keeps scheduler hoisting (and VGPRs) bounded ----
#pragma unroll 2
    for (int c = 0; c < KC; ++c) {
      const float* sp = srcrow + (size_t)(ch * KC + c) * (HH * WW);
      const float4 s0 = *reinterpret_cast<const float4*>(sp);
      const float4 s1 = *reinterpret_cast<const float4*>(sp + 4);
      const float sv[PX] = {s0.x, s0.y, s0.z, s0.w, s1.x, s1.y, s1.z, s1.w};

      // 16-float window: 4 aligned ds_read_b128 from this thread's own row
      const float4* rp =
          reinterpret_cast<const float4*>(&lds[c][row][tx * PX]);
      float win[16];
#pragma unroll
      for (int q = 0; q < 4; ++q) {
        const float4 t = rp[q];
        win[4 * q]     = t.x;
        win[4 * q + 1] = t.y;
        win[4 * q + 2] = t.z;
        win[4 * q + 3] = t.w;
      }

#pragma unroll
      for (int dj = -S; dj <= S; ++dj) {
#pragma unroll
        for (int k = 0; k < PX; ++k)
          acc[dj + S][k] += sv[k] * win[k + S - dj];
      }
    }
  }

  // ---- store: 9 dj x 2 coalesced float4 stores ----
  const size_t HW = (size_t)HH * WW;
  float* op = out + (size_t)b * 81 * HW + (size_t)h * WW + w0;
#pragma unroll
  for (int dj = -S; dj <= S; ++dj) {
    const int o    = ord_idx(di, dj);    // wave-uniform scalar epilogue
    const int slot = dj + S;
    *reinterpret_cast<float4*>(op + (size_t)o * HW) =
        make_float4(acc[slot][0], acc[slot][1], acc[slot][2], acc[slot][3]);
    *reinterpret_cast<float4*>(op + (size_t)o * HW + 4) =
        make_float4(acc[slot][4], acc[slot][5], acc[slot][6], acc[slot][7]);
  }
}

extern "C" void kernel_launch(void* const* d_in, const int* in_sizes, int n_in,
                              void* d_out, int out_size, void* d_ws, size_t ws_size,
                              hipStream_t stream) {
  const float* src = (const float*)d_in[0];
  const float* tgt = (const float*)d_in[1];
  float* out = (float*)d_out;
  // search_range (d_in[2]) is fixed at 4 per setup_inputs; geometry hardcoded.
  dim3 grid(512, 1, 1);                // 2 bx * 32 by * 8 b, swizzled in-kernel
  dim3 block(NTX, NTY, NG);            // 576 threads = 9 waves
  costvol_kernel<<<grid, block, 0, stream>>>(src, tgt, out);
}